// Round 1
// baseline (115.065 us; speedup 1.0000x reference)
//
#include <hip/hip_runtime.h>
#include <hip/hip_bf16.h>

// Fused: embedding-mean + cont matvec/ReLU + masked prefix-mean pooling + MLP(128->64->2)
// One block per sample b. 256 threads = 4 waves; wave g processes rows s = g, g+4, ...
// Lane l (0..63) owns embedding dim d = l.

__global__ __launch_bounds__(256) void mlp_regressor_fused(
    const float* __restrict__ cont_x,   // [B,S,5]
    const int*   __restrict__ cat_x,    // [B,S,7]
    const int*   __restrict__ length,   // [B]
    const float* __restrict__ e0, const float* __restrict__ e1,
    const float* __restrict__ e2, const float* __restrict__ e3,
    const float* __restrict__ e4, const float* __restrict__ e5,
    const float* __restrict__ e6,
    const float* __restrict__ W_cont,   // [5,64]
    const float* __restrict__ b_cont,   // [64]
    const float* __restrict__ W1,       // [128,64]
    const float* __restrict__ b1,       // [64]
    const float* __restrict__ W2,       // [64,2]
    const float* __restrict__ b2,       // [2]
    float*       __restrict__ out,      // [B,2]
    int S)
{
    const int b   = blockIdx.x;
    const int tid = threadIdx.x;
    const int g   = tid >> 6;   // wave id 0..3
    const int l   = tid & 63;   // embedding dim lane
    const int len = length[b];

    // Register-resident column l of W_cont and bias
    const float wc0 = W_cont[0 * 64 + l];
    const float wc1 = W_cont[1 * 64 + l];
    const float wc2 = W_cont[2 * 64 + l];
    const float wc3 = W_cont[3 * 64 + l];
    const float wc4 = W_cont[4 * 64 + l];
    const float bc  = b_cont[l];

    const int*   catp  = cat_x  + (size_t)b * S * 7;
    const float* contp = cont_x + (size_t)b * S * 5;

    float acc_cat  = 0.0f;
    float acc_cont = 0.0f;

    for (int s = g; s < len; s += 4) {
        const int*   cp = catp  + s * 7;
        const float* xp = contp + s * 5;
        const int i0 = cp[0], i1 = cp[1], i2 = cp[2], i3 = cp[3];
        const int i4 = cp[4], i5 = cp[5], i6 = cp[6];
        const float x0 = xp[0], x1 = xp[1], x2 = xp[2], x3 = xp[3], x4 = xp[4];

        float cs = e0[i0 * 64 + l] + e1[i1 * 64 + l] + e2[i2 * 64 + l]
                 + e3[i3 * 64 + l] + e4[i4 * 64 + l] + e5[i5 * 64 + l]
                 + e6[i6 * 64 + l];
        acc_cat += cs;

        float ch = bc;
        ch = fmaf(x0, wc0, ch);
        ch = fmaf(x1, wc1, ch);
        ch = fmaf(x2, wc2, ch);
        ch = fmaf(x3, wc3, ch);
        ch = fmaf(x4, wc4, ch);
        acc_cont += fmaxf(ch, 0.0f);
    }

    __shared__ float part[4][128];
    part[g][l]      = acc_cat;
    part[g][64 + l] = acc_cont;
    __syncthreads();

    __shared__ float pooled[128];
    if (tid < 128) {
        float v = part[0][tid] + part[1][tid] + part[2][tid] + part[3][tid];
        const float inv_len = 1.0f / (float)len;
        v *= inv_len;
        if (tid < 64) v *= (1.0f / 7.0f);   // mean over the 7 tables
        pooled[tid] = v;
    }
    __syncthreads();

    __shared__ float h[64];
    if (tid < 64) {
        float acc = b1[tid];
#pragma unroll 8
        for (int d = 0; d < 128; ++d) {
            acc = fmaf(pooled[d], W1[d * 64 + tid], acc);
        }
        h[tid] = fmaxf(acc, 0.0f);
    }
    __syncthreads();

    if (tid < 2) {
        float acc = b2[tid];
#pragma unroll
        for (int j = 0; j < 64; ++j) {
            acc = fmaf(h[j], W2[j * 2 + tid], acc);
        }
        out[b * 2 + tid] = fmaxf(acc, 0.0f);
    }
}

extern "C" void kernel_launch(void* const* d_in, const int* in_sizes, int n_in,
                              void* d_out, int out_size, void* d_ws, size_t ws_size,
                              hipStream_t stream)
{
    const float* cont_x = (const float*)d_in[0];
    const int*   cat_x  = (const int*)d_in[1];
    const int*   length = (const int*)d_in[2];
    const float* e0     = (const float*)d_in[3];
    const float* e1     = (const float*)d_in[4];
    const float* e2     = (const float*)d_in[5];
    const float* e3     = (const float*)d_in[6];
    const float* e4     = (const float*)d_in[7];
    const float* e5     = (const float*)d_in[8];
    const float* e6     = (const float*)d_in[9];
    const float* W_cont = (const float*)d_in[10];
    const float* b_cont = (const float*)d_in[11];
    const float* W1     = (const float*)d_in[12];
    const float* b1     = (const float*)d_in[13];
    const float* W2     = (const float*)d_in[14];
    const float* b2     = (const float*)d_in[15];
    float*       out    = (float*)d_out;

    const int B = in_sizes[2];                 // 2048
    const int S = in_sizes[0] / (B * 5);       // 512

    hipLaunchKernelGGL(mlp_regressor_fused, dim3(B), dim3(256), 0, stream,
                       cont_x, cat_x, length,
                       e0, e1, e2, e3, e4, e5, e6,
                       W_cont, b_cont, W1, b1, W2, b2,
                       out, S);
}

// Round 2
// 46.479 us; speedup vs baseline: 2.4756x; 2.4756x over previous
//
#include <hip/hip_runtime.h>
#include <hip/hip_bf16.h>

// Fused: embedding-mean + cont matvec/ReLU + masked prefix-mean pooling + MLP(128->64->2)
// One block per sample b, 256 threads = 4 waves.
// Main loop layout: wave g takes 64-row chunks (base = (g + 4k)*64).
//   Stage: lane = row  -> coalesced loads of 7 ids + 5 floats per row.
//   Consume: lanes as (rg = l>>4 row-in-quad, q = l&15 dim-quad); per quad of 4 rows:
//     12 __shfl broadcasts + 7 ds_read_b128 gathers from LDS-resident tables.
// Embedding tables (101 rows x 64 f32 = 25.9 KB) staged in LDS once per block.

#define CARD0 2
#define CARD1 2
#define CARD2 2
#define CARD3 11
#define CARD4 19
#define CARD5 31
#define CARD6 34
// cumulative float offsets of each table (CARD[t]*64)
__constant__ int kOffs_unused; // (offsets are compile-time below)

__global__ __launch_bounds__(256) void mlp_regressor_fused(
    const float* __restrict__ cont_x,   // [B,S,5]
    const int*   __restrict__ cat_x,    // [B,S,7]
    const int*   __restrict__ length,   // [B]
    const float* __restrict__ e0, const float* __restrict__ e1,
    const float* __restrict__ e2, const float* __restrict__ e3,
    const float* __restrict__ e4, const float* __restrict__ e5,
    const float* __restrict__ e6,
    const float* __restrict__ W_cont,   // [5,64]
    const float* __restrict__ b_cont,   // [64]
    const float* __restrict__ W1,       // [128,64]
    const float* __restrict__ b1,       // [64]
    const float* __restrict__ W2,       // [64,2]
    const float* __restrict__ b2,       // [2]
    float*       __restrict__ out,      // [B,2]
    int S)
{
    constexpr int CARD[7] = {CARD0, CARD1, CARD2, CARD3, CARD4, CARD5, CARD6};
    constexpr int OFFS[7] = {0, 128, 256, 384, 1088, 2304, 4288}; // float offsets
    // total floats = 6464 (25856 B)

    __shared__ __align__(16) float elds[6464];
    __shared__ __align__(16) float4 part4[4][32];   // also reused for W1 partials
    __shared__ float pooled[128];
    __shared__ float hvec[64];

    const int b   = blockIdx.x;
    const int tid = threadIdx.x;
    const int g   = tid >> 6;    // wave id 0..3
    const int l   = tid & 63;    // lane
    const int rg  = l >> 4;      // row-in-quad 0..3
    const int q   = l & 15;      // dim-quad: dims 4q..4q+3

    // ---- stage embedding tables into LDS (float4 coalesced) ----
    {
        const float* tabs[7] = {e0, e1, e2, e3, e4, e5, e6};
#pragma unroll
        for (int t = 0; t < 7; ++t) {
            const float4* src = (const float4*)tabs[t];
            float4*       dst = (float4*)(elds + OFFS[t]);
            const int nv = CARD[t] * 16;
            for (int i = tid; i < nv; i += 256) dst[i] = src[i];
        }
    }

    const int len = length[b];

    // per-lane W_cont columns for dims 4q..4q+3
    const float4* Wc4 = (const float4*)W_cont;   // [5][16] float4
    float4 wc0 = Wc4[0 * 16 + q];
    float4 wc1 = Wc4[1 * 16 + q];
    float4 wc2 = Wc4[2 * 16 + q];
    float4 wc3 = Wc4[3 * 16 + q];
    float4 wc4v = Wc4[4 * 16 + q];
    float4 bc4 = ((const float4*)b_cont)[q];

    const int*   catp  = cat_x  + (size_t)b * S * 7;
    const float* contp = cont_x + (size_t)b * S * 5;

    float4 acc_cat  = {0.f, 0.f, 0.f, 0.f};
    float4 acc_cont = {0.f, 0.f, 0.f, 0.f};

    __syncthreads();   // tables staged

    for (int base = g * 64; base < len; base += 256) {
        const int rows = min(64, len - base);

        // coalesced stage: lane = row
        int   id[7];
        float xv[5];
        if (l < rows) {
            const int* cp = catp + (size_t)(base + l) * 7;
#pragma unroll
            for (int t = 0; t < 7; ++t) id[t] = cp[t];
            const float* xp = contp + (size_t)(base + l) * 5;
#pragma unroll
            for (int j = 0; j < 5; ++j) xv[j] = xp[j];
        } else {
#pragma unroll
            for (int t = 0; t < 7; ++t) id[t] = 0;
#pragma unroll
            for (int j = 0; j < 5; ++j) xv[j] = 0.f;
        }

        const int quads = (rows + 3) >> 2;
        for (int r4 = 0; r4 < quads; ++r4) {
            const int rr = r4 * 4 + rg;   // this lane's source row within chunk

            int bid0 = __shfl(id[0], rr);
            int bid1 = __shfl(id[1], rr);
            int bid2 = __shfl(id[2], rr);
            int bid3 = __shfl(id[3], rr);
            int bid4 = __shfl(id[4], rr);
            int bid5 = __shfl(id[5], rr);
            int bid6 = __shfl(id[6], rr);
            float bx0 = __shfl(xv[0], rr);
            float bx1 = __shfl(xv[1], rr);
            float bx2 = __shfl(xv[2], rr);
            float bx3 = __shfl(xv[3], rr);
            float bx4 = __shfl(xv[4], rr);

            const float4* lds4 = (const float4*)elds;
            float4 t0 = lds4[(OFFS[0] >> 2) + bid0 * 16 + q];
            float4 t1 = lds4[(OFFS[1] >> 2) + bid1 * 16 + q];
            float4 t2 = lds4[(OFFS[2] >> 2) + bid2 * 16 + q];
            float4 t3 = lds4[(OFFS[3] >> 2) + bid3 * 16 + q];
            float4 t4 = lds4[(OFFS[4] >> 2) + bid4 * 16 + q];
            float4 t5 = lds4[(OFFS[5] >> 2) + bid5 * 16 + q];
            float4 t6 = lds4[(OFFS[6] >> 2) + bid6 * 16 + q];

            float4 ec;
            ec.x = ((t0.x + t1.x) + (t2.x + t3.x)) + ((t4.x + t5.x) + t6.x);
            ec.y = ((t0.y + t1.y) + (t2.y + t3.y)) + ((t4.y + t5.y) + t6.y);
            ec.z = ((t0.z + t1.z) + (t2.z + t3.z)) + ((t4.z + t5.z) + t6.z);
            ec.w = ((t0.w + t1.w) + (t2.w + t3.w)) + ((t4.w + t5.w) + t6.w);

            float4 ch = bc4;
            ch.x = fmaf(bx0, wc0.x, ch.x); ch.y = fmaf(bx0, wc0.y, ch.y);
            ch.z = fmaf(bx0, wc0.z, ch.z); ch.w = fmaf(bx0, wc0.w, ch.w);
            ch.x = fmaf(bx1, wc1.x, ch.x); ch.y = fmaf(bx1, wc1.y, ch.y);
            ch.z = fmaf(bx1, wc1.z, ch.z); ch.w = fmaf(bx1, wc1.w, ch.w);
            ch.x = fmaf(bx2, wc2.x, ch.x); ch.y = fmaf(bx2, wc2.y, ch.y);
            ch.z = fmaf(bx2, wc2.z, ch.z); ch.w = fmaf(bx2, wc2.w, ch.w);
            ch.x = fmaf(bx3, wc3.x, ch.x); ch.y = fmaf(bx3, wc3.y, ch.y);
            ch.z = fmaf(bx3, wc3.z, ch.z); ch.w = fmaf(bx3, wc3.w, ch.w);
            ch.x = fmaf(bx4, wc4v.x, ch.x); ch.y = fmaf(bx4, wc4v.y, ch.y);
            ch.z = fmaf(bx4, wc4v.z, ch.z); ch.w = fmaf(bx4, wc4v.w, ch.w);

            if (rr < rows) {
                acc_cat.x += ec.x; acc_cat.y += ec.y;
                acc_cat.z += ec.z; acc_cat.w += ec.w;
                acc_cont.x += fmaxf(ch.x, 0.f); acc_cont.y += fmaxf(ch.y, 0.f);
                acc_cont.z += fmaxf(ch.z, 0.f); acc_cont.w += fmaxf(ch.w, 0.f);
            }
        }
    }

    // ---- reduce over rg (lanes ^16, ^32) ----
#pragma unroll
    for (int off = 16; off <= 32; off <<= 1) {
        acc_cat.x += __shfl_xor(acc_cat.x, off);
        acc_cat.y += __shfl_xor(acc_cat.y, off);
        acc_cat.z += __shfl_xor(acc_cat.z, off);
        acc_cat.w += __shfl_xor(acc_cat.w, off);
        acc_cont.x += __shfl_xor(acc_cont.x, off);
        acc_cont.y += __shfl_xor(acc_cont.y, off);
        acc_cont.z += __shfl_xor(acc_cont.z, off);
        acc_cont.w += __shfl_xor(acc_cont.w, off);
    }
    if (rg == 0) {                 // lanes 0..15, l == q
        part4[g][q]      = acc_cat;    // dims 4q..4q+3
        part4[g][16 + q] = acc_cont;   // dims 64+4q..64+4q+3
    }
    __syncthreads();

    float* partf = (float*)part4;   // [4][128]
    if (tid < 128) {
        float v = partf[0 * 128 + tid] + partf[1 * 128 + tid]
                + partf[2 * 128 + tid] + partf[3 * 128 + tid];
        const float inv_len = 1.0f / (float)len;
        v *= inv_len;
        if (tid < 64) v *= (1.0f / 7.0f);
        pooled[tid] = v;
    }
    __syncthreads();

    // ---- h = relu(pooled @ W1 + b1), split 128 dims over 4 segments ----
    {
        const int o   = tid & 63;
        const int seg = tid >> 6;
        float a1 = (seg == 0) ? b1[o] : 0.f;
        const int d0 = seg * 32;
#pragma unroll 8
        for (int i = 0; i < 32; ++i) {
            const int d = d0 + i;
            a1 = fmaf(pooled[d], W1[d * 64 + o], a1);
        }
        partf[seg * 128 + o] = a1;
    }
    __syncthreads();
    if (tid < 64) {
        float hv = partf[tid] + partf[128 + tid] + partf[256 + tid] + partf[384 + tid];
        hvec[tid] = fmaxf(hv, 0.f);
    }
    __syncthreads();

    if (tid < 2) {
        float acc = b2[tid];
#pragma unroll
        for (int j = 0; j < 64; ++j) {
            acc = fmaf(hvec[j], W2[j * 2 + tid], acc);
        }
        out[b * 2 + tid] = fmaxf(acc, 0.f);
    }
}

extern "C" void kernel_launch(void* const* d_in, const int* in_sizes, int n_in,
                              void* d_out, int out_size, void* d_ws, size_t ws_size,
                              hipStream_t stream)
{
    const float* cont_x = (const float*)d_in[0];
    const int*   cat_x  = (const int*)d_in[1];
    const int*   length = (const int*)d_in[2];
    const float* e0     = (const float*)d_in[3];
    const float* e1     = (const float*)d_in[4];
    const float* e2     = (const float*)d_in[5];
    const float* e3     = (const float*)d_in[6];
    const float* e4     = (const float*)d_in[7];
    const float* e5     = (const float*)d_in[8];
    const float* e6     = (const float*)d_in[9];
    const float* W_cont = (const float*)d_in[10];
    const float* b_cont = (const float*)d_in[11];
    const float* W1     = (const float*)d_in[12];
    const float* b1     = (const float*)d_in[13];
    const float* W2     = (const float*)d_in[14];
    const float* b2     = (const float*)d_in[15];
    float*       out    = (float*)d_out;

    const int B = in_sizes[2];                 // 2048
    const int S = in_sizes[0] / (B * 5);       // 512

    hipLaunchKernelGGL(mlp_regressor_fused, dim3(B), dim3(256), 0, stream,
                       cont_x, cat_x, length,
                       e0, e1, e2, e3, e4, e5, e6,
                       W_cont, b_cont, W1, b1, W2, b2,
                       out, S);
}